// Round 1
// baseline (2850.073 us; speedup 1.0000x reference)
//
#include <hip/hip_runtime.h>
#include <math.h>

// CoAttentionFusion: two gated cross-attention blocks + two FF blocks.
// B=8, Sv=1024, St=512, Vd=1024, Td=768, E=512, H=8, D=64.
// Round 1: correct fp32 baseline. All GEMMs: 64x64 tile, 256 thr, 4x4 microtile.

#define HH 8
#define EE 512
#define DDIM 64

__device__ __forceinline__ float gelu_exact(float x) {
  return 0.5f * x * (1.0f + erff(x * 0.70710678118654752f));
}
__device__ __forceinline__ float sigmoidf_(float x) {
  return 1.0f / (1.0f + expf(-x));
}

// ---------------- LayerNorm (optionally fused exact-GELU on output) ---------
template <bool GELU>
__global__ __launch_bounds__(256) void ln_kernel(
    const float* __restrict__ x, const float* __restrict__ g,
    const float* __restrict__ b, float* __restrict__ out, int cols) {
  const int row = blockIdx.x;
  const float* xr = x + (size_t)row * cols;
  float* orow = out + (size_t)row * cols;
  const int tid = threadIdx.x;
  float s = 0.f, ss = 0.f;
  for (int c = tid; c < cols; c += 256) {
    float v = xr[c];
    s += v;
    ss += v * v;
  }
#pragma unroll
  for (int off = 32; off; off >>= 1) {
    s += __shfl_down(s, off, 64);
    ss += __shfl_down(ss, off, 64);
  }
  __shared__ float rs[4], rss[4], stat[2];
  const int lane = tid & 63, wid = tid >> 6;
  if (lane == 0) {
    rs[wid] = s;
    rss[wid] = ss;
  }
  __syncthreads();
  if (tid == 0) {
    float ts = rs[0] + rs[1] + rs[2] + rs[3];
    float tss = rss[0] + rss[1] + rss[2] + rss[3];
    float m = ts / (float)cols;
    float var = tss / (float)cols - m * m;
    stat[0] = m;
    stat[1] = 1.0f / sqrtf(var + 1e-5f);
  }
  __syncthreads();
  const float m = stat[0], inv = stat[1];
  for (int c = tid; c < cols; c += 256) {
    float v = (xr[c] - m) * inv * g[c] + b[c];
    if (GELU) v = gelu_exact(v);
    orow[c] = v;
  }
}

// ---------------- Generic fp32 GEMM: out = epi(A @ W + bias) ----------------
// A: [M,K] row-major (optional concat of A0[M,K0] | A1[M,K-K0])
// W: [K,N] row-major. Tiles exact: M%64==0, N%64==0, K%16==0.
enum { EPI_BIAS = 0, EPI_GELU = 1, EPI_RESID = 2, EPI_GATE = 3 };

template <int EPI, bool CONCAT>
__global__ __launch_bounds__(256) void gemm_kernel(
    const float* __restrict__ A0, const float* __restrict__ A1, int K0, int K,
    const float* __restrict__ W, const float* __restrict__ bias,
    const float* __restrict__ X1, const float* __restrict__ X2,
    float* __restrict__ out, int N) {
  __shared__ float As[16][65];  // [k][row], padded
  __shared__ float Ws[16][64];  // [k][col]
  const int tid = threadIdx.x;
  const int row0 = blockIdx.y * 64, col0 = blockIdx.x * 64;
  const int ar = tid >> 2, a4 = (tid & 3) * 4;
  const int wr = tid >> 4, wc4 = (tid & 15) * 4;
  const int ty = tid >> 4, tx = tid & 15;
  float acc[4][4] = {};
  for (int k0 = 0; k0 < K; k0 += 16) {
    const float* Ap = A0;
    int kb = k0, astr = K0;
    if (CONCAT && k0 >= K0) {
      Ap = A1;
      kb = k0 - K0;
      astr = K - K0;
    }
    float4 av = *(const float4*)(Ap + (size_t)(row0 + ar) * astr + kb + a4);
    As[a4 + 0][ar] = av.x;
    As[a4 + 1][ar] = av.y;
    As[a4 + 2][ar] = av.z;
    As[a4 + 3][ar] = av.w;
    float4 wv = *(const float4*)(W + (size_t)(k0 + wr) * N + col0 + wc4);
    *(float4*)&Ws[wr][wc4] = wv;
    __syncthreads();
#pragma unroll
    for (int kk = 0; kk < 16; ++kk) {
      float a[4], b[4];
#pragma unroll
      for (int i = 0; i < 4; ++i) a[i] = As[kk][ty * 4 + i];
#pragma unroll
      for (int j = 0; j < 4; ++j) b[j] = Ws[kk][tx * 4 + j];
#pragma unroll
      for (int i = 0; i < 4; ++i)
#pragma unroll
        for (int j = 0; j < 4; ++j) acc[i][j] = fmaf(a[i], b[j], acc[i][j]);
    }
    __syncthreads();
  }
#pragma unroll
  for (int i = 0; i < 4; ++i)
#pragma unroll
    for (int j = 0; j < 4; ++j) {
      const int r = row0 + ty * 4 + i, c = col0 + tx * 4 + j;
      const size_t idx = (size_t)r * N + c;
      float v = acc[i][j] + bias[c];
      if (EPI == EPI_GELU) v = gelu_exact(v);
      if (EPI == EPI_RESID) v = X1[idx] + v;
      if (EPI == EPI_GATE) v = X1[idx] + sigmoidf_(v) * X2[idx];
      out[idx] = v;
    }
}

// ---------------- scores[b,h,q,k] = (Q[b,q,h,:] . K[b,k,h,:]) * scale -------
// q: [B,Sq,H,D] (=[B,Sq,E]), k: [B,Sk,H,D]. out: [B,H,Sq,Sk].
__global__ __launch_bounds__(256) void scores_kernel(
    const float* __restrict__ q, const float* __restrict__ k,
    float* __restrict__ out, int Sq, int Sk, float scale) {
  const int bh = blockIdx.z, b = bh >> 3, h = bh & 7;
  const int row0 = blockIdx.y * 64, col0 = blockIdx.x * 64;
  const int tid = threadIdx.x;
  const int ar = tid >> 2, a4 = (tid & 3) * 4;
  const int ty = tid >> 4, tx = tid & 15;
  __shared__ float Qs[16][65];
  __shared__ float Ks[16][65];
  float acc[4][4] = {};
  const size_t qbase = ((size_t)b * Sq + row0) * EE + h * DDIM;
  const size_t kbase = ((size_t)b * Sk + col0) * EE + h * DDIM;
  for (int k0 = 0; k0 < DDIM; k0 += 16) {
    float4 qv = *(const float4*)(q + qbase + (size_t)ar * EE + k0 + a4);
    Qs[a4 + 0][ar] = qv.x;
    Qs[a4 + 1][ar] = qv.y;
    Qs[a4 + 2][ar] = qv.z;
    Qs[a4 + 3][ar] = qv.w;
    float4 kv = *(const float4*)(k + kbase + (size_t)ar * EE + k0 + a4);
    Ks[a4 + 0][ar] = kv.x;
    Ks[a4 + 1][ar] = kv.y;
    Ks[a4 + 2][ar] = kv.z;
    Ks[a4 + 3][ar] = kv.w;
    __syncthreads();
#pragma unroll
    for (int kk = 0; kk < 16; ++kk) {
      float a[4], bb[4];
#pragma unroll
      for (int i = 0; i < 4; ++i) a[i] = Qs[kk][ty * 4 + i];
#pragma unroll
      for (int j = 0; j < 4; ++j) bb[j] = Ks[kk][tx * 4 + j];
#pragma unroll
      for (int i = 0; i < 4; ++i)
#pragma unroll
        for (int j = 0; j < 4; ++j) acc[i][j] = fmaf(a[i], bb[j], acc[i][j]);
    }
    __syncthreads();
  }
#pragma unroll
  for (int i = 0; i < 4; ++i)
#pragma unroll
    for (int j = 0; j < 4; ++j) {
      const size_t r = (size_t)(b * HH + h) * Sq + row0 + ty * 4 + i;
      out[r * Sk + col0 + tx * 4 + j] = acc[i][j] * scale;
    }
}

// ---------------- row softmax in place, row length Sk = PER*256 -------------
template <int PER>
__global__ __launch_bounds__(256) void softmax_kernel(float* __restrict__ p,
                                                      int Sk) {
  float* pr = p + (size_t)blockIdx.x * Sk;
  const int tid = threadIdx.x;
  float vals[PER];
  float mx = -1e30f;
#pragma unroll
  for (int i = 0; i < PER; ++i) {
    vals[i] = pr[tid + i * 256];
    mx = fmaxf(mx, vals[i]);
  }
  __shared__ float red[4];
#pragma unroll
  for (int off = 32; off; off >>= 1) mx = fmaxf(mx, __shfl_down(mx, off, 64));
  const int lane = tid & 63, wid = tid >> 6;
  if (lane == 0) red[wid] = mx;
  __syncthreads();
  mx = fmaxf(fmaxf(red[0], red[1]), fmaxf(red[2], red[3]));
  float s = 0.f;
#pragma unroll
  for (int i = 0; i < PER; ++i) {
    vals[i] = expf(vals[i] - mx);
    s += vals[i];
  }
  __syncthreads();
#pragma unroll
  for (int off = 32; off; off >>= 1) s += __shfl_down(s, off, 64);
  if (lane == 0) red[wid] = s;
  __syncthreads();
  s = red[0] + red[1] + red[2] + red[3];
  const float inv = 1.0f / s;
#pragma unroll
  for (int i = 0; i < PER; ++i) pr[tid + i * 256] = vals[i] * inv;
}

// ---------------- ctx[b,q,h,:] = sum_k w[b,h,q,k] * v[b,k,h,:] --------------
__global__ __launch_bounds__(256) void ctx_kernel(const float* __restrict__ w,
                                                  const float* __restrict__ v,
                                                  float* __restrict__ out,
                                                  int Sq, int Sk) {
  const int bh = blockIdx.z, b = bh >> 3, h = bh & 7;
  const int row0 = blockIdx.y * 64;
  const int tid = threadIdx.x;
  const int ar = tid >> 2, a4 = (tid & 3) * 4;
  const int vr = tid >> 4, vc4 = (tid & 15) * 4;
  const int ty = tid >> 4, tx = tid & 15;
  __shared__ float Ps[16][65];
  __shared__ float Vs[16][64];
  float acc[4][4] = {};
  const float* wb = w + (size_t)bh * Sq * Sk + (size_t)row0 * Sk;
  for (int k0 = 0; k0 < Sk; k0 += 16) {
    float4 pv = *(const float4*)(wb + (size_t)ar * Sk + k0 + a4);
    Ps[a4 + 0][ar] = pv.x;
    Ps[a4 + 1][ar] = pv.y;
    Ps[a4 + 2][ar] = pv.z;
    Ps[a4 + 3][ar] = pv.w;
    float4 vv =
        *(const float4*)(v + ((size_t)b * Sk + k0 + vr) * EE + h * DDIM + vc4);
    *(float4*)&Vs[vr][vc4] = vv;
    __syncthreads();
#pragma unroll
    for (int kk = 0; kk < 16; ++kk) {
      float a[4], bb[4];
#pragma unroll
      for (int i = 0; i < 4; ++i) a[i] = Ps[kk][ty * 4 + i];
#pragma unroll
      for (int j = 0; j < 4; ++j) bb[j] = Vs[kk][tx * 4 + j];
#pragma unroll
      for (int i = 0; i < 4; ++i)
#pragma unroll
        for (int j = 0; j < 4; ++j) acc[i][j] = fmaf(a[i], bb[j], acc[i][j]);
    }
    __syncthreads();
  }
#pragma unroll
  for (int i = 0; i < 4; ++i)
#pragma unroll
    for (int j = 0; j < 4; ++j) {
      out[((size_t)b * Sq + row0 + ty * 4 + i) * EE + h * DDIM + tx * 4 + j] =
          acc[i][j];
    }
}

extern "C" void kernel_launch(void* const* d_in, const int* in_sizes, int n_in,
                              void* d_out, int out_size, void* d_ws,
                              size_t ws_size, hipStream_t stream) {
  (void)in_sizes;
  (void)n_in;
  (void)out_size;
  (void)ws_size;
  const int B = 8, Sv = 1024, St = 512, Vd = 1024, Td = 768;
  auto in = [&](int i) { return (const float*)d_in[i]; };
  const float* vis = in(0);
  const float* txt = in(1);
  float* out = (float*)d_out;
  float* ws = (float*)d_ws;
  // workspace arena (floats): 112 MiB total
  float* A = ws;                  // 8,388,608
  float* Bb = ws + 8388608;       // 8,388,608
  float* C = ws + 16777216;       // 4,194,304
  float* D = ws + 20971520;       // 4,194,304
  float* E = ws + 25165824;       // 4,194,304
  // d_out layout: vision_out, text_out, t2v_w, v2t_w
  float* out_vis = out;            // 8192x512   (also holds vis_att)
  float* out_txt = out + 4194304;  // 4096x512   (also holds text_att)
  float* w_t2v = out + 6291456;    // [8,8,512,1024]
  float* w_v2t = out + 39845888;   // [8,8,1024,512]

  // ================= t2v: text queries attend to vision ====================
  {
    const int pb = 2;  // t2v_ params base
    const int Mq = B * St, Mk = B * Sv;  // 4096, 8192
    ln_kernel<false><<<Mq, 256, 0, stream>>>(txt, in(pb + 0), in(pb + 1), C, Td);
    ln_kernel<false><<<Mk, 256, 0, stream>>>(vis, in(pb + 2), in(pb + 3), A, Vd);
    // q_t -> D, k_v -> E, v_v -> Bb
    gemm_kernel<EPI_BIAS, false><<<dim3(8, Mq / 64), 256, 0, stream>>>(
        C, nullptr, Td, Td, in(pb + 4), in(pb + 5), nullptr, nullptr, D, 512);
    gemm_kernel<EPI_BIAS, false><<<dim3(8, Mk / 64), 256, 0, stream>>>(
        A, nullptr, Vd, Vd, in(pb + 6), in(pb + 7), nullptr, nullptr, E, 512);
    gemm_kernel<EPI_BIAS, false><<<dim3(8, Mk / 64), 256, 0, stream>>>(
        A, nullptr, Vd, Vd, in(pb + 8), in(pb + 9), nullptr, nullptr, Bb, 512);
    scores_kernel<<<dim3(Sv / 64, St / 64, 64), 256, 0, stream>>>(
        D, E, w_t2v, St, Sv, 0.125f);
    softmax_kernel<4><<<64 * St, 256, 0, stream>>>(w_t2v, Sv);
    ctx_kernel<<<dim3(1, St / 64, 64), 256, 0, stream>>>(w_t2v, Bb, C, St, Sv);
    // att_t -> D, qp_t -> E
    gemm_kernel<EPI_BIAS, false><<<dim3(8, Mq / 64), 256, 0, stream>>>(
        C, nullptr, 512, 512, in(pb + 10), in(pb + 11), nullptr, nullptr, D,
        512);
    gemm_kernel<EPI_BIAS, false><<<dim3(8, Mq / 64), 256, 0, stream>>>(
        txt, nullptr, Td, Td, in(pb + 12), in(pb + 13), nullptr, nullptr, E,
        512);
    // h_t = [qp|att] @ g1w -> A ; hg = gelu(ln(h)) -> Bb
    gemm_kernel<EPI_BIAS, true><<<dim3(8, Mq / 64), 256, 0, stream>>>(
        E, D, 512, 1024, in(pb + 14), in(pb + 15), nullptr, nullptr, A, 512);
    ln_kernel<true><<<Mq, 256, 0, stream>>>(A, in(pb + 16), in(pb + 17), Bb,
                                            512);
    // text_att = qp + sigmoid(hg @ g2w + g2b) * att -> out_txt (scratch use)
    gemm_kernel<EPI_GATE, false><<<dim3(8, Mq / 64), 256, 0, stream>>>(
        Bb, nullptr, 512, 512, in(pb + 18), in(pb + 19), E, D, out_txt, 512);
  }
  // ================= v2t: vision queries attend to text ====================
  {
    const int pb = 22;  // v2t_ params base
    const int Mq = B * Sv, Mk = B * St;  // 8192, 4096
    ln_kernel<false><<<Mq, 256, 0, stream>>>(vis, in(pb + 0), in(pb + 1), A, Vd);
    ln_kernel<false><<<Mk, 256, 0, stream>>>(txt, in(pb + 2), in(pb + 3), C, Td);
    // q_v -> E, k_t -> D, v_t -> Bb
    gemm_kernel<EPI_BIAS, false><<<dim3(8, Mq / 64), 256, 0, stream>>>(
        A, nullptr, Vd, Vd, in(pb + 4), in(pb + 5), nullptr, nullptr, E, 512);
    gemm_kernel<EPI_BIAS, false><<<dim3(8, Mk / 64), 256, 0, stream>>>(
        C, nullptr, Td, Td, in(pb + 6), in(pb + 7), nullptr, nullptr, D, 512);
    gemm_kernel<EPI_BIAS, false><<<dim3(8, Mk / 64), 256, 0, stream>>>(
        C, nullptr, Td, Td, in(pb + 8), in(pb + 9), nullptr, nullptr, Bb, 512);
    scores_kernel<<<dim3(St / 64, Sv / 64, 64), 256, 0, stream>>>(
        E, D, w_v2t, Sv, St, 0.125f);
    softmax_kernel<2><<<64 * Sv, 256, 0, stream>>>(w_v2t, St);
    ctx_kernel<<<dim3(1, Sv / 64, 64), 256, 0, stream>>>(w_v2t, Bb, C, Sv, St);
    // att_v -> E, qp_v -> A[0:4M], h_v -> A[4M:8M], hg -> Bb
    gemm_kernel<EPI_BIAS, false><<<dim3(8, Mq / 64), 256, 0, stream>>>(
        C, nullptr, 512, 512, in(pb + 10), in(pb + 11), nullptr, nullptr, E,
        512);
    gemm_kernel<EPI_BIAS, false><<<dim3(8, Mq / 64), 256, 0, stream>>>(
        vis, nullptr, Vd, Vd, in(pb + 12), in(pb + 13), nullptr, nullptr, A,
        512);
    gemm_kernel<EPI_BIAS, true><<<dim3(8, Mq / 64), 256, 0, stream>>>(
        A, E, 512, 1024, in(pb + 14), in(pb + 15), nullptr, nullptr,
        A + 4194304, 512);
    ln_kernel<true><<<Mq, 256, 0, stream>>>(A + 4194304, in(pb + 16),
                                            in(pb + 17), Bb, 512);
    // vis_att = qp + sigmoid(hg @ g2w + g2b) * att -> out_vis (scratch use)
    gemm_kernel<EPI_GATE, false><<<dim3(8, Mq / 64), 256, 0, stream>>>(
        Bb, nullptr, 512, 512, in(pb + 18), in(pb + 19), A, E, out_vis, 512);
  }
  // ================= FF blocks =============================================
  {
    // vff (base 42): vision_out = vis_att + gelu(ln(vis_att)@w1+b1)@w2+b2
    ln_kernel<false><<<8192, 256, 0, stream>>>(out_vis, in(42), in(43), C, 512);
    gemm_kernel<EPI_GELU, false><<<dim3(32, 128), 256, 0, stream>>>(
        C, nullptr, 512, 512, in(44), in(45), nullptr, nullptr, A, 2048);
    gemm_kernel<EPI_RESID, false><<<dim3(8, 128), 256, 0, stream>>>(
        A, nullptr, 2048, 2048, in(46), in(47), out_vis, nullptr, out_vis, 512);
    // tff (base 48)
    ln_kernel<false><<<4096, 256, 0, stream>>>(out_txt, in(48), in(49), C, 512);
    gemm_kernel<EPI_GELU, false><<<dim3(32, 64), 256, 0, stream>>>(
        C, nullptr, 512, 512, in(50), in(51), nullptr, nullptr, A, 2048);
    gemm_kernel<EPI_RESID, false><<<dim3(8, 64), 256, 0, stream>>>(
        A, nullptr, 2048, 2048, in(52), in(53), out_txt, nullptr, out_txt, 512);
  }
}